// Round 3
// baseline (43.861 us; speedup 1.0000x reference)
//
#include <hip/hip_runtime.h>
#include <hip/hip_bf16.h>
#include <math.h>

// QuantumConv2D reduces analytically to:
//   out[b,c,i,j] = prod_{3x3 window} cos(median_padded_x[b,c,...])
// Proof: RY product state -> CNOT chain makes the last qubit the parity of
// all bits -> <Z_last> = <Z0...Z9> = prod_q cos(theta_q); ancilla theta=0
// contributes 1. Product is order-independent, so patch order is irrelevant.
//
// x: (4,3,64,64) fp32 = 12 channels of 64x64. Pad=1 with per-channel lower
// median (sorted[2047] of 4096, torch semantics). Output fp32 (4,3,64,64).
//
// One fused kernel per channel: 4-round radix-select median on sortable
// float keys in LDS, then cos(padded) tile in LDS, then 3x3 product.

#define NCH   12
#define HW    64
#define NPIX  4096   // 64*64
#define PADW  66
#define LDSTR 68     // padded LDS row stride for the cos tile

__device__ __forceinline__ unsigned key_of(float f) {
    unsigned u = __float_as_uint(f);
    return (u & 0x80000000u) ? ~u : (u ^ 0x80000000u);  // monotone map
}

__global__ __launch_bounds__(1024) void qconv_fused(
        const float* __restrict__ x, float* __restrict__ out) {
    __shared__ unsigned keys[NPIX];
    __shared__ unsigned hist[256];
    __shared__ unsigned s_prefix;
    __shared__ int s_k;
    __shared__ float ct[PADW * LDSTR];

    const int ch  = blockIdx.x;
    const int tid = threadIdx.x;
    const float* p = x + ch * NPIX;

    // ---- load keys for median select ----
    for (int i = tid; i < NPIX; i += 1024) keys[i] = key_of(p[i]);
    if (tid == 0) { s_prefix = 0u; s_k = (NPIX - 1) / 2; }  // rank 2047 (lower median)
    __syncthreads();

    // ---- 4-round MSB-first radix select (8 bits/round) ----
    for (int r = 0; r < 4; ++r) {
        const int shift = 24 - 8 * r;
        if (tid < 256) hist[tid] = 0u;
        __syncthreads();
        const unsigned pref = s_prefix;
        for (int i = tid; i < NPIX; i += 1024) {
            unsigned k = keys[i];
            bool match = (r == 0) || ((k >> (shift + 8)) == pref);
            if (match) atomicAdd(&hist[(k >> shift) & 255u], 1u);
        }
        __syncthreads();
        if (tid == 0) {
            int k = s_k;
            unsigned b;
            for (b = 0; b < 256u; ++b) {
                int c = (int)hist[b];
                if (k < c) break;
                k -= c;
            }
            s_k = k;
            s_prefix = (pref << 8) | b;
        }
        __syncthreads();
    }

    const unsigned mu = s_prefix;
    const float medv = __uint_as_float((mu & 0x80000000u) ? (mu ^ 0x80000000u) : ~mu);
    const float cm = cosf(medv);

    // ---- cos(padded) tile in LDS ----
    for (int i = tid; i < PADW * PADW; i += 1024) {
        int r = i / PADW, c = i - r * PADW;
        float v;
        if (r >= 1 && r <= HW && c >= 1 && c <= HW)
            v = cosf(p[(r - 1) * HW + (c - 1)]);
        else
            v = cm;
        ct[r * LDSTR + c] = v;
    }
    __syncthreads();

    // ---- 3x3 product, fp32 output ----
    for (int i = tid; i < NPIX; i += 1024) {
        int r = i >> 6, c = i & 63;
        float prod = 1.0f;
#pragma unroll
        for (int dr = 0; dr < 3; ++dr) {
            const float* row = &ct[(r + dr) * LDSTR + c];
            prod *= row[0] * row[1] * row[2];
        }
        out[ch * NPIX + i] = prod;
    }
}

extern "C" void kernel_launch(void* const* d_in, const int* in_sizes, int n_in,
                              void* d_out, int out_size, void* d_ws, size_t ws_size,
                              hipStream_t stream) {
    const float* x = (const float*)d_in[0];
    float* out = (float*)d_out;
    qconv_fused<<<NCH, 1024, 0, stream>>>(x, out);
}

// Round 4
// 11.844 us; speedup vs baseline: 3.7032x; 3.7032x over previous
//
#include <hip/hip_runtime.h>
#include <math.h>

// QuantumConv2D == out[b,c,i,j] = prod_{3x3 window} cos(median_padded_x)
// (<Z_last> after RY product + CNOT chain = prod_q cos(theta_q); ancilla=0 -> 1).
// 12 channels of 64x64 fp32; pad=1 with per-channel lower median
// (sorted[2047] of 4096); fp32 output.
//
// One fused kernel, 12 blocks x 1024 threads:
//   - float4 load -> sortable keys (LDS) + cos tile interior (LDS)
//   - 4-round radix select with PER-WAVE histograms (kills same-address
//     atomic serialization) and a wave-0 shfl prefix-scan bin search
//     (kills the serial tid0 scan that dominated round 3's 41 us)
//   - border fill with cos(median), 3x3 product, float4 store.

#define NCH   12
#define HW    64
#define NPIX  4096
#define PADW  66
#define LDSTR 68
#define NWAVE 16

__device__ __forceinline__ unsigned key_of(float f) {
    unsigned u = __float_as_uint(f);
    return (u & 0x80000000u) ? ~u : (u ^ 0x80000000u);  // monotone map
}

__global__ __launch_bounds__(1024) void qconv_fused(
        const float* __restrict__ x, float* __restrict__ out) {
    __shared__ __align__(16) unsigned keys[NPIX];        // 16 KB
    __shared__ __align__(16) unsigned hist[NWAVE][256];  // 16 KB
    __shared__ __align__(16) unsigned cum[256];          // 1 KB
    __shared__ float ct[PADW * LDSTR];                   // ~17.5 KB
    __shared__ unsigned s_prefix;
    __shared__ unsigned s_k;

    const int tid  = threadIdx.x;
    const int lane = tid & 63;
    const int wav  = tid >> 6;
    const int ch   = blockIdx.x;
    const float* p = x + ch * NPIX;

    // ---- load 4 pixels/thread: keys + cos-tile interior from registers ----
    float4 v = ((const float4*)p)[tid];
    uint4 kv;
    kv.x = key_of(v.x); kv.y = key_of(v.y); kv.z = key_of(v.z); kv.w = key_of(v.w);
    ((uint4*)keys)[tid] = kv;
    {
        int i = tid * 4;
        int r = (i >> 6) + 1, c = (i & 63) + 1;
        float* dst = &ct[r * LDSTR + c];
        dst[0] = __cosf(v.x); dst[1] = __cosf(v.y);
        dst[2] = __cosf(v.z); dst[3] = __cosf(v.w);
    }
    ((uint4*)&hist[0][0])[tid] = make_uint4(0u, 0u, 0u, 0u);  // zero all hists
    if (tid == 0) { s_prefix = 0u; s_k = (NPIX - 1) / 2; }    // lower-median rank
    __syncthreads();

    // ---- 4-round MSB-first radix select ----
    #pragma unroll
    for (int r = 0; r < 4; ++r) {
        const int shift = 24 - 8 * r;
        const unsigned pref = s_prefix;
        const unsigned kcur = s_k;

        uint4 k4 = ((const uint4*)keys)[tid];
        unsigned* h = hist[wav];
        #define DO(comp) { unsigned kk = (comp); \
            if (r == 0 || (kk >> (shift + 8)) == pref) \
                atomicAdd(&h[(kk >> shift) & 255u], 1u); }
        DO(k4.x) DO(k4.y) DO(k4.z) DO(k4.w)
        #undef DO
        __syncthreads();

        // combine 16 wave-hists -> cum (threads 0..255; bank-friendly layout)
        if (tid < 256) {
            unsigned s = 0;
            #pragma unroll
            for (int w = 0; w < NWAVE; ++w) s += hist[w][tid];
            cum[tid] = s;
        }
        __syncthreads();

        if (wav == 0) {
            // wave-0 parallel bin search: lane owns bins 4l..4l+3
            uint4 hh = ((const uint4*)cum)[lane];
            unsigned s0 = hh.x, s1 = s0 + hh.y, s2 = s1 + hh.z, s3 = s2 + hh.w;
            unsigned sc = s3;
            #pragma unroll
            for (int off = 1; off < 64; off <<= 1) {
                unsigned o = __shfl_up(sc, (unsigned)off);
                if (lane >= off) sc += o;
            }
            unsigned excl = sc - s3;  // keys in bins < 4*lane
            unsigned ej[4] = {excl, excl + s0, excl + s1, excl + s2};
            unsigned ij[4] = {excl + s0, excl + s1, excl + s2, excl + s3};
            #pragma unroll
            for (int j = 0; j < 4; ++j) {
                if (ej[j] <= kcur && kcur < ij[j]) {
                    s_prefix = (pref << 8) | (unsigned)(4 * lane + j);
                    s_k = kcur - ej[j];
                }
            }
        } else if (r < 3) {
            // meanwhile waves 1..15 zero hists for next round
            for (int i = tid - 64; i < 1024; i += 960)
                ((uint4*)&hist[0][0])[i] = make_uint4(0u, 0u, 0u, 0u);
        }
        __syncthreads();
    }

    // ---- border fill with cos(median) ----
    const unsigned mu = s_prefix;
    const float medv = __uint_as_float((mu & 0x80000000u) ? (mu ^ 0x80000000u) : ~mu);
    const float cm = __cosf(medv);
    if (tid < 260) {
        int r, c;
        if (tid < 66)       { r = 0;             c = tid; }
        else if (tid < 132) { r = PADW - 1;      c = tid - 66; }
        else if (tid < 196) { r = tid - 132 + 1; c = 0; }
        else                { r = tid - 196 + 1; c = PADW - 1; }
        ct[r * LDSTR + c] = cm;
    }
    __syncthreads();

    // ---- 3x3 product: 4 consecutive outputs/thread, float4 store ----
    {
        int orow = tid >> 4;          // 0..63
        int oc0  = (tid & 15) * 4;    // 0..60
        float p0 = 1.f, p1 = 1.f, p2 = 1.f, p3 = 1.f;
        #pragma unroll
        for (int dr = 0; dr < 3; ++dr) {
            const float* row = &ct[(orow + dr) * LDSTR + oc0];
            float b0 = row[0], b1 = row[1], b2 = row[2],
                  b3 = row[3], b4 = row[4], b5 = row[5];
            float c12 = b1 * b2, c34 = b3 * b4;
            p0 *= b0 * c12; p1 *= c12 * b3; p2 *= b2 * c34; p3 *= c34 * b5;
        }
        ((float4*)(out + ch * NPIX))[tid] = make_float4(p0, p1, p2, p3);
    }
}

extern "C" void kernel_launch(void* const* d_in, const int* in_sizes, int n_in,
                              void* d_out, int out_size, void* d_ws, size_t ws_size,
                              hipStream_t stream) {
    const float* x = (const float*)d_in[0];
    float* out = (float*)d_out;
    qconv_fused<<<NCH, 1024, 0, stream>>>(x, out);
}